// Round 3
// baseline (1162.712 us; speedup 1.0000x reference)
//
#include <hip/hip_runtime.h>

// Problem constants (MotionDiscreteAE): B=32, N=2048, D=512, S=2, K=1024, DS=256
#define BN_   65536   // B*N
#define K_    1024
#define DS_   256
#define D_    512
#define TM    64      // m-vectors per block (argmin kernel)
#define TK    128     // codes per k-tile

// ---------------------------------------------------------------------------
// Kernel 0: w_sq[s*K + k] = sum_d W[s][k][d]^2  (fp32 chunked; error ~1e-10,
// negligible vs the 1.5e-5 quantization grid of (x_sq + w_sq)).
// ---------------------------------------------------------------------------
__global__ __launch_bounds__(256)
void wsq_kernel(const float* __restrict__ W, float* __restrict__ wsq) {
  const int k = blockIdx.x * 256 + threadIdx.x;  // 0..2047
  const float4* row = (const float4*)(W + (size_t)k * DS_);
  float s0 = 0.f, s1 = 0.f, s2 = 0.f, s3 = 0.f;
#pragma unroll
  for (int i = 0; i < DS_ / 4; ++i) {
    const float4 v = row[i];
    s0 = fmaf(v.x, v.x, s0);
    s1 = fmaf(v.y, v.y, s1);
    s2 = fmaf(v.z, v.z, s2);
    s3 = fmaf(v.w, v.w, s3);
  }
  wsq[k] = (s0 + s1) + (s2 + s3);
}

// ---------------------------------------------------------------------------
// Kernel 0b: xsq[s*BN + m] = np.sum(x*x, -1) BIT-EXACT numpy-pairwise fp32.
// numpy pairwise_sum for n=256 contiguous: pair(a[0:128]) + pair(a[128:256]);
// each 128-block: r[j]=a[j]; for t=1..15: r[j]+=a[8t+j];
// combine ((r0+r1)+(r2+r3))+((r4+r5)+(r6+r7)). No FMA anywhere.
// ---------------------------------------------------------------------------
__global__ __launch_bounds__(256)
void xsq_kernel(const float* __restrict__ h, float* __restrict__ xsq) {
  const int idx = blockIdx.x * 256 + threadIdx.x;  // 0..131071
  const int s = idx >> 16;
  const int m = idx & 0xFFFF;
  const float* x = h + (size_t)m * D_ + s * DS_;
  float blk[2];
#pragma unroll
  for (int b = 0; b < 2; ++b) {
    const float* a = x + b * 128;
    float r[8];
#pragma unroll
    for (int j = 0; j < 8; ++j) r[j] = __fmul_rn(a[j], a[j]);
    for (int t = 1; t < 16; ++t) {
#pragma unroll
      for (int j = 0; j < 8; ++j) {
        const float p = __fmul_rn(a[t * 8 + j], a[t * 8 + j]);
        r[j] = __fadd_rn(r[j], p);
      }
    }
    const float s01 = __fadd_rn(r[0], r[1]);
    const float s23 = __fadd_rn(r[2], r[3]);
    const float s45 = __fadd_rn(r[4], r[5]);
    const float s67 = __fadd_rn(r[6], r[7]);
    blk[b] = __fadd_rn(__fadd_rn(s01, s23), __fadd_rn(s45, s67));
  }
  xsq[idx] = __fadd_rn(blk[0], blk[1]);
}

// ---------------------------------------------------------------------------
// Kernel 1: per (slice s, vector m):
//   argmin_k  D_k = fl32( fl32(xsq_m + wsq_k) - 2*dot(x_m, w_k) )
// emulating the numpy fp32 oracle incl. its quantized ties (argmin tie ->
// lowest index, as np.argmin). LDS: xs 64 KiB + wst 16 KiB -> 2 blocks/CU.
// Also emits per-block sum of bestD (= ||x - w_best||^2) for the VQ loss.
// ---------------------------------------------------------------------------
__global__ __launch_bounds__(256, 2)
void argmin_kernel(const float* __restrict__ h, const float* __restrict__ W,
                   const float* __restrict__ wsq, const float* __restrict__ xsq,
                   int* __restrict__ ids, float* __restrict__ partials) {
  __shared__ float xs[DS_][TM];   // [d][m], 64 KiB
  __shared__ float wst[32][TK];   // [d][k], 16 KiB
  // overlay candidate buffers onto wst between d-loops (protected by syncs)
  float* candv = &wst[0][0];        // 1024 floats: per-thread best D
  int*   candi = (int*)&wst[8][0];  // 1024 ints:   per-thread best index

  const int tid = threadIdx.x;
  const int m0  = blockIdx.x * TM;
  const int s   = blockIdx.y;

  // ---- stage x tile, transposed to [d][m] ----
  {
    const int m  = tid & 63;
    const int dg = tid >> 6;  // 0..3
    const float* xrow = h + (size_t)(m0 + m) * D_ + s * DS_;
#pragma unroll
    for (int it = 0; it < 16; ++it) {
      const int d = it * 16 + dg * 4;
      const float4 v = *(const float4*)(xrow + d);
      xs[d + 0][m] = v.x;
      xs[d + 1][m] = v.y;
      xs[d + 2][m] = v.z;
      xs[d + 3][m] = v.w;
    }
  }

  const int tx = tid & 15;  // m-group: covers m = tx*4 .. tx*4+3
  const int ty = tid >> 4;  // k-group: covers k = ty*8 .. ty*8+7
  const float* __restrict__ wsq_s = wsq + s * K_;
  const float* __restrict__ Wb    = W + (size_t)s * K_ * DS_;

  // per-m oracle x_sq (bit-exact numpy value), for this thread's 4 m
  float Xq[4];
#pragma unroll
  for (int i = 0; i < 4; ++i) Xq[i] = xsq[s * BN_ + m0 + tx * 4 + i];

  float bestv = 3.4e38f;  // running best D (valid on tid<64: m = m0+tid)
  int   besti = 0;

  for (int k0 = 0; k0 < K_; k0 += TK) {
    float acc[4][8];
#pragma unroll
    for (int i = 0; i < 4; ++i)
#pragma unroll
      for (int j = 0; j < 8; ++j) acc[i][j] = 0.f;

    for (int dc = 0; dc < 8; ++dc) {
      __syncthreads();  // xs staged / wst+cand free
      {                 // stage W tile [32 d][128 k]
        const int k    = tid & 127;
        const int half = tid >> 7;  // 0..1
        const float* wrow = Wb + (size_t)(k0 + k) * DS_ + dc * 32 + half * 16;
#pragma unroll
        for (int it = 0; it < 4; ++it) {
          const float4 v = *(const float4*)(wrow + it * 4);
          const int d = half * 16 + it * 4;
          wst[d + 0][k] = v.x;
          wst[d + 1][k] = v.y;
          wst[d + 2][k] = v.z;
          wst[d + 3][k] = v.w;
        }
      }
      __syncthreads();

      // chunk-local accumulator (keeps dot error ~1e-9, far below the
      // 1.5e-5 quantization grid)
      float acct[4][8];
#pragma unroll
      for (int i = 0; i < 4; ++i)
#pragma unroll
        for (int j = 0; j < 8; ++j) acct[i][j] = 0.f;

#pragma unroll
      for (int d = 0; d < 32; ++d) {
        const float4 a  = *(const float4*)&xs[dc * 32 + d][tx * 4];
        const float4 b0 = *(const float4*)&wst[d][ty * 8];
        const float4 b1 = *(const float4*)&wst[d][ty * 8 + 4];
        const float av[4] = {a.x, a.y, a.z, a.w};
        const float bv[8] = {b0.x, b0.y, b0.z, b0.w, b1.x, b1.y, b1.z, b1.w};
#pragma unroll
        for (int i = 0; i < 4; ++i)
#pragma unroll
          for (int j = 0; j < 8; ++j)
            acct[i][j] = fmaf(av[i], bv[j], acct[i][j]);
      }
#pragma unroll
      for (int i = 0; i < 4; ++i)
#pragma unroll
        for (int j = 0; j < 8; ++j) acc[i][j] += acct[i][j];
    }

    __syncthreads();  // done with wst as W-tile; reuse as candidate buffer
    // Oracle-emulated distance: D = fl32( fl32(Xsq + wsq_k) - 2*dot ).
    // 2*acc is exact (power of two). Strict < keeps the lowest index.
#pragma unroll
    for (int i = 0; i < 4; ++i) {
      float lv = 3.4e38f;
      int   li = 0;
#pragma unroll
      for (int j = 0; j < 8; ++j) {
        const int kk = k0 + ty * 8 + j;
        const float t1 = __fadd_rn(Xq[i], wsq_s[kk]);
        const float dv = __fsub_rn(t1, 2.0f * acc[i][j]);
        if (dv < lv) { lv = dv; li = kk; }
      }
      candv[ty * TM + tx * 4 + i] = lv;
      candi[ty * TM + tx * 4 + i] = li;
    }
    __syncthreads();
    if (tid < TM) {  // wave 0: merge 16 candidates per m (ascending k order)
#pragma unroll
      for (int t = 0; t < 16; ++t) {
        const float v = candv[t * TM + tid];
        if (v < bestv) { bestv = v; besti = candi[t * TM + tid]; }
      }
    }
  }

  if (tid < TM) {
    ids[s * BN_ + m0 + tid] = besti;
    // VQ-loss partial: bestv == quantized ||x - w_best||^2 (threshold is
    // enormous for vq_total, fp32 is plenty)
    float v = bestv;
#pragma unroll
    for (int off = 32; off > 0; off >>= 1) v += __shfl_down(v, off);
    if (tid == 0) partials[blockIdx.y * 1024 + blockIdx.x] = v;
  }
}

// ---------------------------------------------------------------------------
// Kernel 2: z[m][d] = W[s][ids[s][m]][d mod 256];  out_ids[m] = id0 + 1024*id1
// ---------------------------------------------------------------------------
__global__ __launch_bounds__(256)
void gather_kernel(const float* __restrict__ W, const int* __restrict__ ids,
                   float* __restrict__ out) {
  const int tid = threadIdx.x;
  float* out_ids = out + (size_t)BN_ * D_;
#pragma unroll
  for (int it = 0; it < 4; ++it) {
    const size_t i4 = (size_t)it * 2097152 + (size_t)blockIdx.x * 256 + tid;
    const size_t e  = i4 * 4;               // element index into [BN, 512]
    const int m  = (int)(e >> 9);
    const int d  = (int)(e & 511);
    const int s  = d >> 8;
    const int dd = d & 255;
    const int id = ids[s * BN_ + m];
    const float4 z = *(const float4*)(W + ((size_t)(s * K_ + id)) * DS_ + dd);
    *(float4*)(out + e) = z;
    if (d == 0) {  // one thread per m writes the packed id (as float value)
      const int id1 = ids[BN_ + m];
      out_ids[m] = (float)(id + (id1 << 10));
    }
  }
}

// ---------------------------------------------------------------------------
// Kernel 3: vq_total = 1.25 * sum(partials) / (BN*DS)
// ---------------------------------------------------------------------------
__global__ __launch_bounds__(256)
void finalize_kernel(const float* __restrict__ partials,
                     float* __restrict__ out_vq) {
  __shared__ float red[256];
  const int tid = threadIdx.x;
  float s = 0.f;
  for (int i = tid; i < 2048; i += 256) s += partials[i];
  red[tid] = s;
  __syncthreads();
  for (int off = 128; off > 0; off >>= 1) {
    if (tid < off) red[tid] += red[tid + off];
    __syncthreads();
  }
  if (tid == 0) out_vq[0] = red[0] * (1.25f / 16777216.f);
}

// ---------------------------------------------------------------------------
extern "C" void kernel_launch(void* const* d_in, const int* in_sizes, int n_in,
                              void* d_out, int out_size, void* d_ws,
                              size_t ws_size, hipStream_t stream) {
  const float* h = (const float*)d_in[0];  // [BN, 512]
  const float* W = (const float*)d_in[1];  // [2, 1024, 256]
  float* out  = (float*)d_out;             // z | ids(as float) | vq_total
  float* wsf  = (float*)d_ws;
  float* wsq      = wsf;                   // 2048 floats
  float* partials = wsf + 2048;            // 2048 floats
  int*   ids      = (int*)(wsf + 4096);    // 131072 ints
  float* xsq      = wsf + 4096 + 131072;   // 131072 floats

  wsq_kernel<<<8, 256, 0, stream>>>(W, wsq);
  xsq_kernel<<<512, 256, 0, stream>>>(h, xsq);
  argmin_kernel<<<dim3(1024, 2), 256, 0, stream>>>(h, W, wsq, xsq, ids,
                                                   partials);
  gather_kernel<<<8192, 256, 0, stream>>>(W, ids, out);
  finalize_kernel<<<1, 256, 0, stream>>>(partials,
                                         out + (size_t)BN_ * D_ + BN_);
}

// Round 4
// 1090.804 us; speedup vs baseline: 1.0659x; 1.0659x over previous
//
#include <hip/hip_runtime.h>

// Problem constants (MotionDiscreteAE): B=32, N=2048, D=512, S=2, K=1024, DS=256
#define BN_   65536   // B*N
#define K_    1024
#define DS_   256
#define D_    512
#define TM    64      // m-vectors per block (argmin kernel)
#define TK    128     // codes per k-tile

// ---------------------------------------------------------------------------
// Kernel 0: w_sq[s*K + k] = sum_d W[s][k][d]^2  (fp32 chunked; error ~1e-10,
// negligible vs the 1.5e-5 quantization grid of (x_sq + w_sq)).
// ---------------------------------------------------------------------------
__global__ __launch_bounds__(256)
void wsq_kernel(const float* __restrict__ W, float* __restrict__ wsq) {
  const int k = blockIdx.x * 256 + threadIdx.x;  // 0..2047
  const float4* row = (const float4*)(W + (size_t)k * DS_);
  float s0 = 0.f, s1 = 0.f, s2 = 0.f, s3 = 0.f;
#pragma unroll
  for (int i = 0; i < DS_ / 4; ++i) {
    const float4 v = row[i];
    s0 = fmaf(v.x, v.x, s0);
    s1 = fmaf(v.y, v.y, s1);
    s2 = fmaf(v.z, v.z, s2);
    s3 = fmaf(v.w, v.w, s3);
  }
  wsq[k] = (s0 + s1) + (s2 + s3);
}

// ---------------------------------------------------------------------------
// Kernel 0b: xsq[s*BN + m] = np.sum(x*x, -1) BIT-EXACT numpy-pairwise fp32.
// numpy pairwise_sum for n=256 contiguous: pair(a[0:128]) + pair(a[128:256]);
// each 128-block: r[j]=a[j]; for t=1..15: r[j]+=a[8t+j];
// combine ((r0+r1)+(r2+r3))+((r4+r5)+(r6+r7)). No FMA anywhere.
// ---------------------------------------------------------------------------
__global__ __launch_bounds__(256)
void xsq_kernel(const float* __restrict__ h, float* __restrict__ xsq) {
  const int idx = blockIdx.x * 256 + threadIdx.x;  // 0..131071
  const int s = idx >> 16;
  const int m = idx & 0xFFFF;
  const float* x = h + (size_t)m * D_ + s * DS_;
  float blk[2];
#pragma unroll
  for (int b = 0; b < 2; ++b) {
    const float* a = x + b * 128;
    float r[8];
#pragma unroll
    for (int j = 0; j < 8; ++j) r[j] = __fmul_rn(a[j], a[j]);
    for (int t = 1; t < 16; ++t) {
#pragma unroll
      for (int j = 0; j < 8; ++j) {
        const float p = __fmul_rn(a[t * 8 + j], a[t * 8 + j]);
        r[j] = __fadd_rn(r[j], p);
      }
    }
    const float s01 = __fadd_rn(r[0], r[1]);
    const float s23 = __fadd_rn(r[2], r[3]);
    const float s45 = __fadd_rn(r[4], r[5]);
    const float s67 = __fadd_rn(r[6], r[7]);
    blk[b] = __fadd_rn(__fadd_rn(s01, s23), __fadd_rn(s45, s67));
  }
  xsq[idx] = __fadd_rn(blk[0], blk[1]);
}

// ---------------------------------------------------------------------------
// Kernel 1: per (slice s, vector m):
//   argmin_k  D_k = fl32( fl32(xsq_m + wsq_k) - 2*dot(x_m, w_k) )
// Bit-identical distance math to round 3 (same chunking / FMA order).
// R4 changes (perf only):
//  - W-tile staged via register prefetch: next chunk's global loads issue
//    before the current chunk's compute, hiding L2 latency under the FMAs.
//  - Flattened chunk loop (64 chunks = 8 k-tiles x 8 d-chunks).
//  - Per-thread running best across k-tiles; single merge at the end with
//    lexicographic (value, index) compare == np.argmin global lowest-index.
// LDS: xs 64 KiB + wst 16 KiB -> 2 blocks/CU.
// ---------------------------------------------------------------------------
__global__ __launch_bounds__(256, 2)
void argmin_kernel(const float* __restrict__ h, const float* __restrict__ W,
                   const float* __restrict__ wsq, const float* __restrict__ xsq,
                   int* __restrict__ ids, float* __restrict__ partials) {
  __shared__ float xs[DS_][TM];   // [d][m], 64 KiB
  __shared__ float wst[32][TK];   // [d][k], 16 KiB
  // candidate buffers overlay wst (used only after the chunk loop)
  float* candv = &wst[0][0];        // 1024 floats: per-thread best D
  int*   candi = (int*)&wst[8][0];  // 1024 ints:   per-thread best index

  const int tid = threadIdx.x;
  const int m0  = blockIdx.x * TM;
  const int s   = blockIdx.y;

  // ---- stage x tile, transposed to [d][m] ----
  {
    const int m  = tid & 63;
    const int dg = tid >> 6;  // 0..3
    const float* xrow = h + (size_t)(m0 + m) * D_ + s * DS_;
#pragma unroll
    for (int it = 0; it < 16; ++it) {
      const int d = it * 16 + dg * 4;
      const float4 v = *(const float4*)(xrow + d);
      xs[d + 0][m] = v.x;
      xs[d + 1][m] = v.y;
      xs[d + 2][m] = v.z;
      xs[d + 3][m] = v.w;
    }
  }

  const int tx = tid & 15;  // m-group: covers m = tx*4 .. tx*4+3
  const int ty = tid >> 4;  // k-group: covers k = ty*8 .. ty*8+7 per tile
  const float* __restrict__ wsq_s = wsq + s * K_;
  const float* __restrict__ Wb    = W + (size_t)s * K_ * DS_;

  // per-m oracle x_sq (bit-exact numpy value), for this thread's 4 m
  float Xq[4];
#pragma unroll
  for (int i = 0; i < 4; ++i) Xq[i] = xsq[s * BN_ + m0 + tx * 4 + i];

  // staging identity: this thread stages W row (k0 + sk), d-halfwindow sh
  const int sk = tid & 127;
  const int sh = tid >> 7;  // 0..1
  const float* wbase = Wb + (size_t)sk * DS_ + sh * 16;

  // initial prefetch: chunk 0 (k0=0, dc=0) — 64 B contiguous per thread
  float4 pre[4];
  {
    const float4* p = (const float4*)wbase;
    pre[0] = p[0]; pre[1] = p[1]; pre[2] = p[2]; pre[3] = p[3];
  }

  float bestv[4];
  int   besti[4];
#pragma unroll
  for (int i = 0; i < 4; ++i) { bestv[i] = 3.4e38f; besti[i] = 0x7fffffff; }

  float acc[4][8];
#pragma unroll
  for (int i = 0; i < 4; ++i)
#pragma unroll
    for (int j = 0; j < 8; ++j) acc[i][j] = 0.f;

  // ---- 64 chunks = 8 k-tiles x 8 d-chunks ----
  for (int c = 0; c < 64; ++c) {
    const int dc = c & 7;
    __syncthreads();  // all waves done reading wst for previous chunk
    {                 // dump prefetched regs into wst[d][k]
      const float* pf = (const float*)pre;  // d = dc*32 + sh*16 + t
#pragma unroll
      for (int t = 0; t < 16; ++t) wst[sh * 16 + t][sk] = pf[t];
    }
    __syncthreads();  // wst ready
    {                 // issue async prefetch for the NEXT chunk
      const int cn  = (c < 63) ? c + 1 : 63;
      const float4* p = (const float4*)(wbase +
          (size_t)((cn >> 3) * TK) * DS_ + (cn & 7) * 32);
      pre[0] = p[0]; pre[1] = p[1]; pre[2] = p[2]; pre[3] = p[3];
    }

    // chunk-local accumulator (same rounding order as round 3)
    float acct[4][8];
#pragma unroll
    for (int i = 0; i < 4; ++i)
#pragma unroll
      for (int j = 0; j < 8; ++j) acct[i][j] = 0.f;

#pragma unroll
    for (int d = 0; d < 32; ++d) {
      const float4 a  = *(const float4*)&xs[dc * 32 + d][tx * 4];
      const float4 b0 = *(const float4*)&wst[d][ty * 8];
      const float4 b1 = *(const float4*)&wst[d][ty * 8 + 4];
      const float av[4] = {a.x, a.y, a.z, a.w};
      const float bv[8] = {b0.x, b0.y, b0.z, b0.w, b1.x, b1.y, b1.z, b1.w};
#pragma unroll
      for (int i = 0; i < 4; ++i)
#pragma unroll
        for (int j = 0; j < 8; ++j)
          acct[i][j] = fmaf(av[i], bv[j], acct[i][j]);
    }
#pragma unroll
    for (int i = 0; i < 4; ++i)
#pragma unroll
      for (int j = 0; j < 8; ++j) acc[i][j] += acct[i][j];

    if (dc == 7) {  // k-tile complete: fold into per-thread running best
      const int k0 = (c >> 3) * TK;
#pragma unroll
      for (int i = 0; i < 4; ++i) {
#pragma unroll
        for (int j = 0; j < 8; ++j) {  // j ascending; tiles ascending =>
          const int kk = k0 + ty * 8 + j;  // this thread's k's ascend: strict <
          const float t1 = __fadd_rn(Xq[i], wsq_s[kk]);
          const float dv = __fsub_rn(t1, 2.0f * acc[i][j]);
          if (dv < bestv[i]) { bestv[i] = dv; besti[i] = kk; }
        }
        acc[i][0] = 0.f; acc[i][1] = 0.f; acc[i][2] = 0.f; acc[i][3] = 0.f;
        acc[i][4] = 0.f; acc[i][5] = 0.f; acc[i][6] = 0.f; acc[i][7] = 0.f;
      }
    }
  }

  // ---- final merge (once): lexicographic (value, index) == np.argmin ----
  __syncthreads();  // wst free for candidate overlay
#pragma unroll
  for (int i = 0; i < 4; ++i) {
    candv[ty * TM + tx * 4 + i] = bestv[i];
    candi[ty * TM + tx * 4 + i] = besti[i];
  }
  __syncthreads();
  if (tid < TM) {
    float bv = 3.4e38f;
    int   bi = 0x7fffffff;
#pragma unroll
    for (int t = 0; t < 16; ++t) {
      const float v = candv[t * TM + tid];
      const int   c = candi[t * TM + tid];
      if (v < bv || (v == bv && c < bi)) { bv = v; bi = c; }
    }
    ids[s * BN_ + m0 + tid] = bi;
    // VQ-loss partial: bv == quantized ||x - w_best||^2
    float v = bv;
#pragma unroll
    for (int off = 32; off > 0; off >>= 1) v += __shfl_down(v, off);
    if (tid == 0) partials[blockIdx.y * 1024 + blockIdx.x] = v;
  }
}

// ---------------------------------------------------------------------------
// Kernel 2: z[m][d] = W[s][ids[s][m]][d mod 256];  out_ids[m] = id0 + 1024*id1
// ---------------------------------------------------------------------------
__global__ __launch_bounds__(256)
void gather_kernel(const float* __restrict__ W, const int* __restrict__ ids,
                   float* __restrict__ out) {
  const int tid = threadIdx.x;
  float* out_ids = out + (size_t)BN_ * D_;
#pragma unroll
  for (int it = 0; it < 4; ++it) {
    const size_t i4 = (size_t)it * 2097152 + (size_t)blockIdx.x * 256 + tid;
    const size_t e  = i4 * 4;               // element index into [BN, 512]
    const int m  = (int)(e >> 9);
    const int d  = (int)(e & 511);
    const int s  = d >> 8;
    const int dd = d & 255;
    const int id = ids[s * BN_ + m];
    const float4 z = *(const float4*)(W + ((size_t)(s * K_ + id)) * DS_ + dd);
    *(float4*)(out + e) = z;
    if (d == 0) {  // one thread per m writes the packed id (as float value)
      const int id1 = ids[BN_ + m];
      out_ids[m] = (float)(id + (id1 << 10));
    }
  }
}

// ---------------------------------------------------------------------------
// Kernel 3: vq_total = 1.25 * sum(partials) / (BN*DS)
// ---------------------------------------------------------------------------
__global__ __launch_bounds__(256)
void finalize_kernel(const float* __restrict__ partials,
                     float* __restrict__ out_vq) {
  __shared__ float red[256];
  const int tid = threadIdx.x;
  float s = 0.f;
  for (int i = tid; i < 2048; i += 256) s += partials[i];
  red[tid] = s;
  __syncthreads();
  for (int off = 128; off > 0; off >>= 1) {
    if (tid < off) red[tid] += red[tid + off];
    __syncthreads();
  }
  if (tid == 0) out_vq[0] = red[0] * (1.25f / 16777216.f);
}

// ---------------------------------------------------------------------------
extern "C" void kernel_launch(void* const* d_in, const int* in_sizes, int n_in,
                              void* d_out, int out_size, void* d_ws,
                              size_t ws_size, hipStream_t stream) {
  const float* h = (const float*)d_in[0];  // [BN, 512]
  const float* W = (const float*)d_in[1];  // [2, 1024, 256]
  float* out  = (float*)d_out;             // z | ids(as float) | vq_total
  float* wsf  = (float*)d_ws;
  float* wsq      = wsf;                   // 2048 floats
  float* partials = wsf + 2048;            // 2048 floats
  int*   ids      = (int*)(wsf + 4096);    // 131072 ints
  float* xsq      = wsf + 4096 + 131072;   // 131072 floats

  wsq_kernel<<<8, 256, 0, stream>>>(W, wsq);
  xsq_kernel<<<512, 256, 0, stream>>>(h, xsq);
  argmin_kernel<<<dim3(1024, 2), 256, 0, stream>>>(h, W, wsq, xsq, ids,
                                                   partials);
  gather_kernel<<<8192, 256, 0, stream>>>(W, ids, out);
  finalize_kernel<<<1, 256, 0, stream>>>(partials,
                                         out + (size_t)BN_ * D_ + BN_);
}